// Round 9
// baseline (121748.804 us; speedup 1.0000x reference)
//
#include <hip/hip_runtime.h>
#include <math.h>
#include <stdint.h>

namespace {

constexpr int TT = 256;   // timesteps
constexpr int HH = 512;   // hidden

// ---- ws layout (floats) ----
constexpr size_t OFF_STATE = 0;                      // h0,c0,h1,c1 [4][512][64]
constexpr size_t OFF_FZ0 = 131072;                   // [640][64]
constexpr size_t OFF_FS0 = OFF_FZ0 + 40960;
constexpr size_t OFF_FB0 = OFF_FS0 + 40960;          // [640][8][64]
constexpr size_t OFF_FZ1 = OFF_FB0 + 327680;         // [1024][64]
constexpr size_t OFF_FS1 = OFF_FZ1 + 65536;
constexpr size_t OFF_FB1 = OFF_FS1 + 65536;          // [1024][8][64]
constexpr size_t OFF_P0  = OFF_FB1 + 524288;         // [6144][64]
constexpr size_t OFF_P1  = OFF_P0 + 393216;
constexpr size_t OFF_SWT0= OFF_P1 + 393216;          // [8][512][640]
constexpr size_t OFF_SWT1= OFF_SWT0 + 2621440;       // [8][512][1024]
constexpr size_t OFF_BAR = OFF_SWT1 + 4194304;       // 1024 uints (barrier state)
constexpr size_t WS_NEED = (OFF_BAR + 1024) * 4;     // ~33.6 MB

struct KParams {
    const float *x, *w_ih0, *w_hh0, *b_ih0, *b_hh0, *kb0, *ksp0;
    const float *w_ih1, *w_hh1, *b_ih1, *b_hh1, *kb1, *ksp1;
    const float *fc_w, *fc_b;
    float* ws;
    float* out;
};

__device__ __forceinline__ float sigmoidf_(float v) { return 1.0f / (1.0f + expf(-v)); }

// Cox-de Boor, GRID_SIZE=5, ORDER=3 -> 12 knots, 8 basis functions. (verified)
__device__ __forceinline__ void bspline8(float x, float* out) {
    const float KG[12] = {-2.2f,-1.8f,-1.4f,-1.0f,-0.6f,-0.2f,
                           0.2f, 0.6f, 1.0f, 1.4f, 1.8f, 2.2f};
    float b[11];
#pragma unroll
    for (int i = 0; i < 11; ++i)
        b[i] = (x >= KG[i] && x < KG[i + 1]) ? 1.0f : 0.0f;
#pragma unroll
    for (int p = 1; p <= 3; ++p) {
#pragma unroll
        for (int i = 0; i + p < 11; ++i) {
            float l = (x - KG[i])         * (1.0f / (KG[i + p] - KG[i]));
            float r = (KG[i + p + 1] - x) * (1.0f / (KG[i + p + 1] - KG[i + 1]));
            b[i] = l * b[i] + r * b[i + 1];
        }
    }
#pragma unroll
    for (int i = 0; i < 8; ++i) out[i] = b[i];
}

__device__ __forceinline__ void write_feats(float z, int k, int b,
        float* __restrict__ fz, float* __restrict__ fs, float* __restrict__ fb) {
    fz[(size_t)k * 64 + b] = z;
    fs[(size_t)k * 64 + b] = z / (1.0f + expf(-z));
    float bs[8];
    bspline8(z, bs);
#pragma unroll
    for (int r = 0; r < 8; ++r) fb[((size_t)k * 8 + r) * 64 + b] = bs[r];
}

// wave-uniform weight row (w) dotted against per-lane feature stream
__device__ __forceinline__ float dotrow(const float* __restrict__ w,
                                        const float* __restrict__ f,
                                        int fstride, int lane, int K) {
    float acc0 = 0.f, acc1 = 0.f;
    for (int k = 0; k < K; k += 8) {
        float4 wa = *(const float4*)(w + k);
        float4 wb = *(const float4*)(w + k + 4);
        float f0 = f[(size_t)(k + 0) * fstride + lane];
        float f1 = f[(size_t)(k + 1) * fstride + lane];
        float f2 = f[(size_t)(k + 2) * fstride + lane];
        float f3 = f[(size_t)(k + 3) * fstride + lane];
        float f4 = f[(size_t)(k + 4) * fstride + lane];
        float f5 = f[(size_t)(k + 5) * fstride + lane];
        float f6 = f[(size_t)(k + 6) * fstride + lane];
        float f7 = f[(size_t)(k + 7) * fstride + lane];
        acc0 = fmaf(f0, wa.x, acc0); acc1 = fmaf(f1, wa.y, acc1);
        acc0 = fmaf(f2, wa.z, acc0); acc1 = fmaf(f3, wa.w, acc1);
        acc0 = fmaf(f4, wb.x, acc0); acc1 = fmaf(f5, wb.y, acc1);
        acc0 = fmaf(f6, wb.z, acc0); acc1 = fmaf(f7, wb.w, acc1);
    }
    return acc0 + acc1;
}

// Two-level device-scope grid barrier. bar[0]=root cnt, bar[8]=generation,
// group counters at bar[16 + g*16] (64B apart). Requires gridDim.x % 32 == 0
// and all blocks co-resident.
__device__ __forceinline__ void grid_barrier(unsigned* bar) {
    __threadfence();
    __syncthreads();
    if (threadIdx.x == 0) {
        const unsigned gsize = gridDim.x >> 5;
        const int grp = blockIdx.x & 31;
        unsigned gen = __hip_atomic_load(&bar[8], __ATOMIC_ACQUIRE, __HIP_MEMORY_SCOPE_AGENT);
        unsigned a = __hip_atomic_fetch_add(&bar[16 + grp * 16], 1u,
                        __ATOMIC_ACQ_REL, __HIP_MEMORY_SCOPE_AGENT) + 1;
        if (a == gsize) {
            __hip_atomic_store(&bar[16 + grp * 16], 0u, __ATOMIC_RELAXED, __HIP_MEMORY_SCOPE_AGENT);
            unsigned ra = __hip_atomic_fetch_add(&bar[0], 1u,
                            __ATOMIC_ACQ_REL, __HIP_MEMORY_SCOPE_AGENT) + 1;
            if (ra == 32u) {
                __hip_atomic_store(&bar[0], 0u, __ATOMIC_RELAXED, __HIP_MEMORY_SCOPE_AGENT);
                __hip_atomic_fetch_add(&bar[8], 1u, __ATOMIC_RELEASE, __HIP_MEMORY_SCOPE_AGENT);
            }
        }
        while (__hip_atomic_load(&bar[8], __ATOMIC_ACQUIRE, __HIP_MEMORY_SCOPE_AGENT) == gen)
            __builtin_amdgcn_s_sleep(1);
    }
    __syncthreads();
}

__global__ __launch_bounds__(64) void zero_bar(unsigned* bar) {
    for (int i = threadIdx.x; i < 1024; i += 64) bar[i] = 0u;
}

__global__ __launch_bounds__(256) void sentinel_kernel(float* out, float v) {
    int i = blockIdx.x * 256 + threadIdx.x;
    if (i < 8192) out[i] = v;
}

__global__ __launch_bounds__(256, 4) void kan_lstm_persist(KParams P) {
    float* ws  = P.ws;
    float* h0  = ws + OFF_STATE;
    float* c0  = h0 + 32768;
    float* h1  = c0 + 32768;
    float* c1  = h1 + 32768;
    float* fz0 = ws + OFF_FZ0; float* fs0 = ws + OFF_FS0; float* fb0 = ws + OFF_FB0;
    float* fz1 = ws + OFF_FZ1; float* fs1 = ws + OFF_FS1; float* fb1 = ws + OFF_FB1;
    float* p0  = ws + OFF_P0;  float* p1  = ws + OFF_P1;
    float* swT0 = ws + OFF_SWT0; float* swT1 = ws + OFF_SWT1;
    unsigned* bar = (unsigned*)(ws + OFF_BAR);

    const int tid  = blockIdx.x * 256 + threadIdx.x;
    const int nth  = gridDim.x * 256;
    const int lane = threadIdx.x & 63;
    const int nwaves = nth >> 6;

    // ---- prologue: states, swT transposes, t=0 features, h1(-1)=0 features ----
    for (int i = tid; i < 4 * 32768; i += nth) h0[i] = 0.f;
    for (int i = tid; i < 512 * 640; i += nth) {
        float v[8];
#pragma unroll
        for (int r = 0; r < 8; ++r) v[r] = P.ksp0[(size_t)i * 8 + r];
#pragma unroll
        for (int r = 0; r < 8; ++r) swT0[(size_t)r * 327680 + i] = v[r];
    }
    for (int i = tid; i < 512 * 1024; i += nth) {
        float v[8];
#pragma unroll
        for (int r = 0; r < 8; ++r) v[r] = P.ksp1[(size_t)i * 8 + r];
#pragma unroll
        for (int r = 0; r < 8; ++r) swT1[(size_t)r * 524288 + i] = v[r];
    }
    for (int i = tid; i < 640 * 64; i += nth) {
        int k = i >> 6, b = i & 63;
        float z = (k < 128) ? P.x[((size_t)b * TT) * 128 + k] : 0.0f;
        write_feats(z, k, b, fz0, fs0, fb0);
    }
    for (int i = tid; i < 512 * 64; i += nth) {
        int k = i >> 6, b = i & 63;
        write_feats(0.0f, 512 + k, b, fz1, fs1, fb1);
    }
    grid_barrier(bar);

    // ---- skewed pipeline: iter s does gemm L0(t=s) + L1(t=s-1) ----
    for (int s = 0; s <= TT; ++s) {
        const bool doL0 = (s < TT), doL1 = (s >= 1);

        // phase A: all dot-product rows (12288 = 2 layers x 6144)
        for (int row = (tid >> 6); row < 12288; row += nwaves) {
            const bool isL1 = row >= 6144;
            if (isL1 ? !doL1 : !doL0) continue;
            const int r = __builtin_amdgcn_readfirstlane(isL1 ? row - 6144 : row);
            const int IN = isL1 ? 512 : 128;
            const int W = IN + 512;
            float acc;
            if (r < 1536) {
                const float* wih = (isL1 ? P.w_ih1 : P.w_ih0) + (size_t)r * IN;
                const float* whh = (isL1 ? P.w_hh1 : P.w_hh0) + (size_t)r * 512;
                const float* fz = isL1 ? fz1 : fz0;
                acc = dotrow(wih, fz, 64, lane, IN)
                    + dotrow(whh, fz + (size_t)IN * 64, 64, lane, 512);
            } else if (r < 2048) {
                const int o = r - 1536;
                acc = dotrow((isL1 ? P.kb1 : P.kb0) + (size_t)o * W,
                             isL1 ? fs1 : fs0, 64, lane, W);
            } else {
                const int rr = (r - 2048) >> 9, o = (r - 2048) & 511;
                acc = dotrow((isL1 ? swT1 : swT0) + ((size_t)rr * 512 + o) * W,
                             (isL1 ? fb1 : fb0) + rr * 64, 512, lane, W);
            }
            (isL1 ? p1 : p0)[(size_t)r * 64 + lane] = acc;
        }
        grid_barrier(bar);

        // phase B: updates + all feature generation (73728 items)
        for (int u = tid; u < 73728; u += nth) {
            if (u < 32768) {
                if (!doL0) continue;
                const int o = u >> 6, b = u & 63;
                float si = p0[(size_t)o*64+b]         + P.b_ih0[o]      + P.b_hh0[o];
                float sf = p0[(size_t)(512+o)*64+b]   + P.b_ih0[512+o]  + P.b_hh0[512+o];
                float sO = p0[(size_t)(1024+o)*64+b]  + P.b_ih0[1024+o] + P.b_hh0[1024+o];
                float sk = p0[(size_t)(1536+o)*64+b];
#pragma unroll
                for (int rr = 0; rr < 8; ++rr)
                    sk += p0[(size_t)(2048 + rr*512 + o)*64 + b];
                float ig = sigmoidf_(si), fg = sigmoidf_(sf), og = sigmoidf_(sO);
                float c = fg * c0[(size_t)o*64+b] + ig * sk;
                c0[(size_t)o*64+b] = c;
                float z = og * tanhf(c);
                h0[(size_t)o*64+b] = z;
                write_feats(z, o, b, fz1, fs1, fb1);        // L1 input features, t=s
                write_feats(z, 128 + o, b, fz0, fs0, fb0);  // L0 hidden features, t=s+1
            } else if (u < 65536) {
                if (!doL1) continue;
                const int v = u - 32768, o = v >> 6, b = v & 63;
                float si = p1[(size_t)o*64+b]         + P.b_ih1[o]      + P.b_hh1[o];
                float sf = p1[(size_t)(512+o)*64+b]   + P.b_ih1[512+o]  + P.b_hh1[512+o];
                float sO = p1[(size_t)(1024+o)*64+b]  + P.b_ih1[1024+o] + P.b_hh1[1024+o];
                float sk = p1[(size_t)(1536+o)*64+b];
#pragma unroll
                for (int rr = 0; rr < 8; ++rr)
                    sk += p1[(size_t)(2048 + rr*512 + o)*64 + b];
                float ig = sigmoidf_(si), fg = sigmoidf_(sf), og = sigmoidf_(sO);
                float c = fg * c1[(size_t)o*64+b] + ig * sk;
                c1[(size_t)o*64+b] = c;
                float z = og * tanhf(c);
                h1[(size_t)o*64+b] = z;
                write_feats(z, 512 + o, b, fz1, fs1, fb1);  // L1 hidden features, t=s
            } else {
                if (s + 1 < TT) {
                    const int v = u - 65536, k = v >> 6, b = v & 63;
                    float z = P.x[((size_t)b * TT + (s + 1)) * 128 + k];
                    write_feats(z, k, b, fz0, fs0, fb0);    // L0 x features, t=s+1
                }
            }
        }
        grid_barrier(bar);
    }

    // ---- final fc: out[b][jo] = h1 . fc_w[jo] + fc_b[jo] ----
    for (int u = tid; u < 8192; u += nth) {
        const int b = u & 63, jo = u >> 6;
        float a = P.fc_b[jo];
        for (int o = 0; o < 512; ++o)
            a = fmaf(h1[(size_t)o * 64 + b], P.fc_w[(size_t)jo * 512 + o], a);
        P.out[(size_t)b * 128 + jo] = a;
    }
}

} // namespace

extern "C" void kernel_launch(void* const* d_in, const int* in_sizes, int n_in,
                              void* d_out, int out_size, void* d_ws, size_t ws_size,
                              hipStream_t stream) {
    (void)out_size;
    float* out = (float*)d_out;

    static const int EXP_SIZES[15] = {
        64 * 256 * 128, 1536 * 128, 1536 * 512, 1536, 1536,
        512 * 640, 512 * 640 * 8,
        1536 * 512, 1536 * 512, 1536, 1536,
        512 * 1024, 512 * 1024 * 8,
        128 * 512, 128
    };
    if (n_in != 15) { sentinel_kernel<<<32, 256, 0, stream>>>(out, 111.0f); return; }
    for (int i = 0; i < 15; ++i)
        if (in_sizes[i] != EXP_SIZES[i]) {
            sentinel_kernel<<<32, 256, 0, stream>>>(out, 200.0f * (i + 1)); return;
        }
    if (ws_size < WS_NEED) { sentinel_kernel<<<32, 256, 0, stream>>>(out, 7777.0f); return; }

    KParams kp;
    kp.x     = (const float*)d_in[0];
    kp.w_ih0 = (const float*)d_in[1];
    kp.w_hh0 = (const float*)d_in[2];
    kp.b_ih0 = (const float*)d_in[3];
    kp.b_hh0 = (const float*)d_in[4];
    kp.kb0   = (const float*)d_in[5];
    kp.ksp0  = (const float*)d_in[6];
    kp.w_ih1 = (const float*)d_in[7];
    kp.w_hh1 = (const float*)d_in[8];
    kp.b_ih1 = (const float*)d_in[9];
    kp.b_hh1 = (const float*)d_in[10];
    kp.kb1   = (const float*)d_in[11];
    kp.ksp1  = (const float*)d_in[12];
    kp.fc_w  = (const float*)d_in[13];
    kp.fc_b  = (const float*)d_in[14];
    kp.ws    = (float*)d_ws;
    kp.out   = out;

    // grid size: all blocks must be co-resident (hand-rolled grid barrier)
    int occ = 0;
    hipError_t e = hipOccupancyMaxActiveBlocksPerMultiprocessor(&occ, kan_lstm_persist, 256, 0);
    int NB = (e == hipSuccess && occ > 0) ? occ * 256 : 256;   // 256 CUs on MI355X
    if (NB > 1024) NB = 1024;
    NB &= ~31;                    // barrier needs multiple of 32
    if (NB < 32) NB = 32;

    unsigned* bar = (unsigned*)((float*)d_ws + OFF_BAR);
    zero_bar<<<1, 64, 0, stream>>>(bar);
    kan_lstm_persist<<<NB, 256, 0, stream>>>(kp);
}

// Round 10
// 31498.181 us; speedup vs baseline: 3.8653x; 3.8653x over previous
//
#include <hip/hip_runtime.h>
#include <math.h>

namespace {

constexpr int TT = 256;   // timesteps

// ---- ws layout (floats), total 8,798,208 floats = 35.19 MB (== round-8 budget, proven) ----
constexpr size_t OFF_STATE = 0;                      // h0,c0,h1,c1 [4][512][64]
constexpr size_t OFF_FZ0 = 131072;                   // [640][64]
constexpr size_t OFF_FS0 = OFF_FZ0 + 40960;
constexpr size_t OFF_FB0 = OFF_FS0 + 40960;          // [640][8][64]
constexpr size_t OFF_FZ1 = OFF_FB0 + 327680;         // [1024][64]
constexpr size_t OFF_FS1 = OFF_FZ1 + 65536;
constexpr size_t OFF_FB1 = OFF_FS1 + 65536;          // [1024][8][64]
constexpr size_t OFF_P0  = OFF_FB1 + 524288;         // [6144][64]
constexpr size_t OFF_P1  = OFF_P0 + 393216;          // [6144][64]
constexpr size_t OFF_SWT0= OFF_P1 + 393216;          // [8][512][640]
constexpr size_t OFF_SWT1= OFF_SWT0 + 2621440;       // [8][512][1024]
constexpr size_t WS_NEED = (OFF_SWT1 + 4194304) * 4;

__device__ __forceinline__ float sigmoidf_(float v) { return 1.0f / (1.0f + expf(-v)); }

// Cox-de Boor, GRID_SIZE=5, ORDER=3 -> 12 knots, 8 basis functions. (verified)
__device__ __forceinline__ void bspline8(float x, float* out) {
    const float KG[12] = {-2.2f,-1.8f,-1.4f,-1.0f,-0.6f,-0.2f,
                           0.2f, 0.6f, 1.0f, 1.4f, 1.8f, 2.2f};
    float b[11];
#pragma unroll
    for (int i = 0; i < 11; ++i)
        b[i] = (x >= KG[i] && x < KG[i + 1]) ? 1.0f : 0.0f;
#pragma unroll
    for (int p = 1; p <= 3; ++p) {
#pragma unroll
        for (int i = 0; i + p < 11; ++i) {
            float l = (x - KG[i])         * (1.0f / (KG[i + p] - KG[i]));
            float r = (KG[i + p + 1] - x) * (1.0f / (KG[i + p + 1] - KG[i + 1]));
            b[i] = l * b[i] + r * b[i + 1];
        }
    }
#pragma unroll
    for (int i = 0; i < 8; ++i) out[i] = b[i];
}

__device__ __forceinline__ void write_feats(float z, int k, int b,
        float* __restrict__ fz, float* __restrict__ fs, float* __restrict__ fb) {
    fz[(size_t)k * 64 + b] = z;
    fs[(size_t)k * 64 + b] = z / (1.0f + expf(-z));
    float bs[8];
    bspline8(z, bs);
#pragma unroll
    for (int r = 0; r < 8; ++r) fb[((size_t)k * 8 + r) * 64 + b] = bs[r];
}

__global__ __launch_bounds__(256) void sentinel_kernel(float* out, float v) {
    int i = blockIdx.x * 256 + threadIdx.x;
    if (i < 8192) out[i] = v;
}

// states zero + t=0 layer0 features + layer1 hidden-half features (h1(-1)=0)
__global__ __launch_bounds__(256) void prologue_kernel(
    const float* __restrict__ x, float* __restrict__ ws)
{
    const int g = blockIdx.x * 256 + threadIdx.x;   // 800*256 = 204800
    if (g < 131072) {
        ws[OFF_STATE + g] = 0.0f;                    // h0,c0,h1,c1
    } else if (g < 131072 + 40960) {
        const int i = g - 131072, k = i >> 6, b = i & 63;
        float z = (k < 128) ? x[((size_t)b * TT) * 128 + k] : 0.0f;
        write_feats(z, k, b, ws + OFF_FZ0, ws + OFF_FS0, ws + OFF_FB0);
    } else {
        const int i = g - 131072 - 40960, k = i >> 6, b = i & 63;  // 32768 items
        write_feats(0.0f, 512 + k, b, ws + OFF_FZ1, ws + OFF_FS1, ws + OFF_FB1);
    }
}

// sw [512][W][8] -> swT [8][512][W]
template <int W>
__global__ __launch_bounds__(256) void transpose_sw(const float* __restrict__ sw,
                                                    float* __restrict__ swT) {
    const int i = blockIdx.x * 256 + threadIdx.x;   // over 512*W
    float v[8];
#pragma unroll
    for (int r = 0; r < 8; ++r) v[r] = sw[(size_t)i * 8 + r];
#pragma unroll
    for (int r = 0; r < 8; ++r) swT[(size_t)r * 512 * W + i] = v[r];
}

// 4 rows (shared feature stream) x full-K dot products
__device__ __forceinline__ void dot4(const float* __restrict__ w0, int wstride,
                                     const float* __restrict__ f, int fstride,
                                     int lane, int K, float* __restrict__ acc) {
    for (int k = 0; k < K; k += 8) {
        float f8[8];
#pragma unroll
        for (int u = 0; u < 8; ++u) f8[u] = f[(size_t)(k + u) * fstride + lane];
#pragma unroll
        for (int j = 0; j < 4; ++j) {
            const float* wp = w0 + (size_t)j * wstride + k;
            float4 wa = *(const float4*)wp;
            float4 wb = *(const float4*)(wp + 4);
            acc[j] = fmaf(f8[0], wa.x, acc[j]); acc[j] = fmaf(f8[1], wa.y, acc[j]);
            acc[j] = fmaf(f8[2], wa.z, acc[j]); acc[j] = fmaf(f8[3], wa.w, acc[j]);
            acc[j] = fmaf(f8[4], wb.x, acc[j]); acc[j] = fmaf(f8[5], wb.y, acc[j]);
            acc[j] = fmaf(f8[6], wb.z, acc[j]); acc[j] = fmaf(f8[7], wb.w, acc[j]);
        }
    }
}

// phase A: all 12288 dot rows for L0(t=s) and L1(t=s-1). 768 blocks x 4 waves.
// wave w: layer = w>=1536 (within 0..3071), r4 = (w%1536)*4. Row types:
// r4<1536 gates; 1536..2047 silu(base); 2048..6143 spline (rr=(r4-2048)>>9).
__global__ __launch_bounds__(256) void phaseA_kernel(
    const float* __restrict__ ws_c,
    const float* __restrict__ w_ih0, const float* __restrict__ w_hh0,
    const float* __restrict__ kb0,
    const float* __restrict__ w_ih1, const float* __restrict__ w_hh1,
    const float* __restrict__ kb1,
    float* __restrict__ p0, float* __restrict__ p1, int s)
{
    const int lane = threadIdx.x & 63;
    const int w = blockIdx.x * 4 + (threadIdx.x >> 6);   // 0..3071
    const bool isL1 = w >= 1536;
    if (isL1 ? (s < 1) : (s >= TT)) return;
    const int r4 = __builtin_amdgcn_readfirstlane((isL1 ? w - 1536 : w) * 4);

    const int IN = isL1 ? 512 : 128;
    const int W  = IN + 512;
    const float* fz = ws_c + (isL1 ? OFF_FZ1 : OFF_FZ0);
    const float* fs = ws_c + (isL1 ? OFF_FS1 : OFF_FS0);
    const float* fb = ws_c + (isL1 ? OFF_FB1 : OFF_FB0);
    const float* swT = ws_c + (isL1 ? OFF_SWT1 : OFF_SWT0);

    float acc[4] = {0.f, 0.f, 0.f, 0.f};

    if (r4 < 1536) {
        const float* wih = (isL1 ? w_ih1 : w_ih0) + (size_t)r4 * IN;
        const float* whh = (isL1 ? w_hh1 : w_hh0) + (size_t)r4 * 512;
        dot4(wih, IN, fz, 64, lane, IN, acc);
        dot4(whh, 512, fz + (size_t)IN * 64, 64, lane, 512, acc);
    } else if (r4 < 2048) {
        const int o0 = r4 - 1536;
        dot4((isL1 ? kb1 : kb0) + (size_t)o0 * W, W, fs, 64, lane, W, acc);
    } else {
        const int rr = (r4 - 2048) >> 9, o0 = (r4 - 2048) & 511;
        dot4(swT + ((size_t)rr * 512 + o0) * W, W, fb + rr * 64, 512, lane, W, acc);
    }

    float* p = isL1 ? p1 : p0;
#pragma unroll
    for (int j = 0; j < 4; ++j)
        p[(size_t)(r4 + j) * 64 + lane] = acc[j];
}

// phase B: L0 cell update (t=s) + L1 cell update (t=s-1) + feature generation.
__global__ __launch_bounds__(256) void phaseB_kernel(
    float* __restrict__ ws,
    const float* __restrict__ b_ih0, const float* __restrict__ b_hh0,
    const float* __restrict__ b_ih1, const float* __restrict__ b_hh1,
    const float* __restrict__ x, int s)
{
    float* h0 = ws + OFF_STATE;
    float* c0 = h0 + 32768;
    float* h1 = c0 + 32768;
    float* c1 = h1 + 32768;
    float* fz0 = ws + OFF_FZ0; float* fs0 = ws + OFF_FS0; float* fb0 = ws + OFF_FB0;
    float* fz1 = ws + OFF_FZ1; float* fs1 = ws + OFF_FS1; float* fb1 = ws + OFF_FB1;
    const float* p0 = ws + OFF_P0;
    const float* p1 = ws + OFF_P1;

    const int u = blockIdx.x * 256 + threadIdx.x;   // 288*256 = 73728
    if (u < 32768) {
        if (s >= TT) return;
        const int o = u >> 6, b = u & 63;
        float si = p0[(size_t)o*64+b]        + b_ih0[o]      + b_hh0[o];
        float sf = p0[(size_t)(512+o)*64+b]  + b_ih0[512+o]  + b_hh0[512+o];
        float sO = p0[(size_t)(1024+o)*64+b] + b_ih0[1024+o] + b_hh0[1024+o];
        float sk = p0[(size_t)(1536+o)*64+b];
#pragma unroll
        for (int rr = 0; rr < 8; ++rr)
            sk += p0[(size_t)(2048 + rr*512 + o)*64 + b];
        float ig = sigmoidf_(si), fg = sigmoidf_(sf), og = sigmoidf_(sO);
        float c = fg * c0[(size_t)o*64+b] + ig * sk;
        c0[(size_t)o*64+b] = c;
        float z = og * tanhf(c);
        h0[(size_t)o*64+b] = z;
        write_feats(z, o, b, fz1, fs1, fb1);        // L1 input features, t=s
        write_feats(z, 128 + o, b, fz0, fs0, fb0);  // L0 hidden features, t=s+1
    } else if (u < 65536) {
        if (s < 1) return;
        const int v = u - 32768, o = v >> 6, b = v & 63;
        float si = p1[(size_t)o*64+b]        + b_ih1[o]      + b_hh1[o];
        float sf = p1[(size_t)(512+o)*64+b]  + b_ih1[512+o]  + b_hh1[512+o];
        float sO = p1[(size_t)(1024+o)*64+b] + b_ih1[1024+o] + b_hh1[1024+o];
        float sk = p1[(size_t)(1536+o)*64+b];
#pragma unroll
        for (int rr = 0; rr < 8; ++rr)
            sk += p1[(size_t)(2048 + rr*512 + o)*64 + b];
        float ig = sigmoidf_(si), fg = sigmoidf_(sf), og = sigmoidf_(sO);
        float c = fg * c1[(size_t)o*64+b] + ig * sk;
        c1[(size_t)o*64+b] = c;
        float z = og * tanhf(c);
        h1[(size_t)o*64+b] = z;
        write_feats(z, 512 + o, b, fz1, fs1, fb1);  // L1 hidden features, t=s
    } else {
        if (s + 1 >= TT) return;
        const int v = u - 65536, k = v >> 6, b = v & 63;
        float z = x[((size_t)b * TT + (s + 1)) * 128 + k];
        write_feats(z, k, b, fz0, fs0, fb0);        // L0 x features, t=s+1
    }
}

// out[b][jo] = sum_o h1[o][b] * fc_w[jo][o] + fc_b[jo]  (fp32 out)
__global__ __launch_bounds__(256) void final_fc(
    const float* __restrict__ hT1, const float* __restrict__ fc_w,
    const float* __restrict__ fc_b, float* __restrict__ out)
{
    const int gid = blockIdx.x * 256 + threadIdx.x;   // 8192
    const int b = gid & 63, jo = gid >> 6;
    float a = fc_b[jo];
    for (int o = 0; o < 512; ++o)
        a = fmaf(hT1[(size_t)o * 64 + b], fc_w[(size_t)jo * 512 + o], a);
    out[(size_t)b * 128 + jo] = a;
}

} // namespace

extern "C" void kernel_launch(void* const* d_in, const int* in_sizes, int n_in,
                              void* d_out, int out_size, void* d_ws, size_t ws_size,
                              hipStream_t stream) {
    (void)out_size;
    float* out = (float*)d_out;

    static const int EXP_SIZES[15] = {
        64 * 256 * 128, 1536 * 128, 1536 * 512, 1536, 1536,
        512 * 640, 512 * 640 * 8,
        1536 * 512, 1536 * 512, 1536, 1536,
        512 * 1024, 512 * 1024 * 8,
        128 * 512, 128
    };
    if (n_in != 15) { sentinel_kernel<<<32, 256, 0, stream>>>(out, 111.0f); return; }
    for (int i = 0; i < 15; ++i)
        if (in_sizes[i] != EXP_SIZES[i]) {
            sentinel_kernel<<<32, 256, 0, stream>>>(out, 200.0f * (i + 1)); return;
        }
    if (ws_size < WS_NEED) { sentinel_kernel<<<32, 256, 0, stream>>>(out, 7777.0f); return; }

    const float* x     = (const float*)d_in[0];
    const float* w_ih0 = (const float*)d_in[1];
    const float* w_hh0 = (const float*)d_in[2];
    const float* b_ih0 = (const float*)d_in[3];
    const float* b_hh0 = (const float*)d_in[4];
    const float* kb0   = (const float*)d_in[5];
    const float* ksp0  = (const float*)d_in[6];
    const float* w_ih1 = (const float*)d_in[7];
    const float* w_hh1 = (const float*)d_in[8];
    const float* b_ih1 = (const float*)d_in[9];
    const float* b_hh1 = (const float*)d_in[10];
    const float* kb1   = (const float*)d_in[11];
    const float* ksp1  = (const float*)d_in[12];
    const float* fc_w  = (const float*)d_in[13];
    const float* fc_b  = (const float*)d_in[14];

    float* ws = (float*)d_ws;
    float* p0 = ws + OFF_P0;
    float* p1 = ws + OFF_P1;

    prologue_kernel<<<800, 256, 0, stream>>>(x, ws);
    transpose_sw<640><<<1280, 256, 0, stream>>>(ksp0, ws + OFF_SWT0);
    transpose_sw<1024><<<2048, 256, 0, stream>>>(ksp1, ws + OFF_SWT1);

    for (int s = 0; s <= TT; ++s) {
        phaseA_kernel<<<768, 256, 0, stream>>>(
            ws, w_ih0, w_hh0, kb0, w_ih1, w_hh1, kb1, p0, p1, s);
        phaseB_kernel<<<288, 256, 0, stream>>>(
            ws, b_ih0, b_hh0, b_ih1, b_hh1, x, s);
    }

    final_fc<<<32, 256, 0, stream>>>(ws + OFF_STATE + 2 * 32768, fc_w, fc_b, out);
}

// Round 11
// 23467.561 us; speedup vs baseline: 5.1880x; 1.3422x over previous
//
#include <hip/hip_runtime.h>
#include <math.h>

namespace {

constexpr int TT = 256;   // timesteps

// ---- ws layout (floats), total 9,699,328 floats = 38.8 MB ----
constexpr size_t OFF_STATE = 0;                      // h0,c0,h1,c1 [4][512][64]
constexpr size_t OFF_FZ0 = 131072;                   // [640][64]
constexpr size_t OFF_FS0 = OFF_FZ0 + 40960;
constexpr size_t OFF_FB0 = OFF_FS0 + 40960;          // [640][8][64]
constexpr size_t OFF_FZ1 = OFF_FB0 + 327680;         // [1024][64]
constexpr size_t OFF_FS1 = OFF_FZ1 + 65536;
constexpr size_t OFF_FB1 = OFF_FS1 + 65536;          // [1024][8][64]
constexpr size_t OFF_P0  = OFF_FB1 + 524288;         // [2][6144][64]
constexpr size_t OFF_P1  = OFF_P0 + 786432;          // [2][6144][64]
constexpr size_t OFF_SWT0= OFF_P1 + 786432;          // [8][512][640]
constexpr size_t OFF_SWT1= OFF_SWT0 + 2621440;       // [8][512][1024]
constexpr size_t WS_NEED = (OFF_SWT1 + 4194304) * 4;
constexpr size_t PSLICE  = 6144 * 64;                // one K-half slice of p

__device__ __forceinline__ float sigmoidf_(float v) { return 1.0f / (1.0f + expf(-v)); }

// Cox-de Boor, GRID_SIZE=5, ORDER=3 -> 12 knots, 8 basis functions. (verified)
__device__ __forceinline__ void bspline8(float x, float* out) {
    const float KG[12] = {-2.2f,-1.8f,-1.4f,-1.0f,-0.6f,-0.2f,
                           0.2f, 0.6f, 1.0f, 1.4f, 1.8f, 2.2f};
    float b[11];
#pragma unroll
    for (int i = 0; i < 11; ++i)
        b[i] = (x >= KG[i] && x < KG[i + 1]) ? 1.0f : 0.0f;
#pragma unroll
    for (int p = 1; p <= 3; ++p) {
#pragma unroll
        for (int i = 0; i + p < 11; ++i) {
            float l = (x - KG[i])         * (1.0f / (KG[i + p] - KG[i]));
            float r = (KG[i + p + 1] - x) * (1.0f / (KG[i + p + 1] - KG[i + 1]));
            b[i] = l * b[i] + r * b[i + 1];
        }
    }
#pragma unroll
    for (int i = 0; i < 8; ++i) out[i] = b[i];
}

__device__ __forceinline__ void write_feats(float z, int k, int b,
        float* __restrict__ fz, float* __restrict__ fs, float* __restrict__ fb) {
    fz[(size_t)k * 64 + b] = z;
    fs[(size_t)k * 64 + b] = z / (1.0f + expf(-z));
    float bs[8];
    bspline8(z, bs);
#pragma unroll
    for (int r = 0; r < 8; ++r) fb[((size_t)k * 8 + r) * 64 + b] = bs[r];
}

__global__ __launch_bounds__(256) void sentinel_kernel(float* out, float v) {
    int i = blockIdx.x * 256 + threadIdx.x;
    if (i < 8192) out[i] = v;
}

// states zero + t=0 layer0 features + layer1 hidden-half features (h1(-1)=0)
__global__ __launch_bounds__(256) void prologue_kernel(
    const float* __restrict__ x, float* __restrict__ ws)
{
    const int g = blockIdx.x * 256 + threadIdx.x;   // 800*256 = 204800
    if (g < 131072) {
        ws[OFF_STATE + g] = 0.0f;
    } else if (g < 131072 + 40960) {
        const int i = g - 131072, k = i >> 6, b = i & 63;
        float z = (k < 128) ? x[((size_t)b * TT) * 128 + k] : 0.0f;
        write_feats(z, k, b, ws + OFF_FZ0, ws + OFF_FS0, ws + OFF_FB0);
    } else {
        const int i = g - 131072 - 40960, k = i >> 6, b = i & 63;  // 32768 items
        write_feats(0.0f, 512 + k, b, ws + OFF_FZ1, ws + OFF_FS1, ws + OFF_FB1);
    }
}

// sw [512][W][8] -> swT [8][512][W]
template <int W>
__global__ __launch_bounds__(256) void transpose_sw(const float* __restrict__ sw,
                                                    float* __restrict__ swT) {
    const int i = blockIdx.x * 256 + threadIdx.x;   // over 512*W
    float v[8];
#pragma unroll
    for (int r = 0; r < 8; ++r) v[r] = sw[(size_t)i * 8 + r];
#pragma unroll
    for (int r = 0; r < 8; ++r) swT[(size_t)r * 512 * W + i] = v[r];
}

// phase A: LDS-tiled GEMM. 768 blocks = [L0|L1][khalf][192 tiles].
// Tile = 32 rows of ONE feature group (4 waves x 8 rows); 64-k feature chunks
// staged in LDS once, each ds_read feeds 8 FMAs. Partials [khalf][6144][64].
__global__ __launch_bounds__(256) void phaseA_kernel(
    float* __restrict__ ws,
    const float* __restrict__ w_ih0, const float* __restrict__ w_hh0,
    const float* __restrict__ kb0,
    const float* __restrict__ w_ih1, const float* __restrict__ w_hh1,
    const float* __restrict__ kb1, int s)
{
    __shared__ float sf[64 * 64];   // 16 KB

    const int bid = blockIdx.x;
    const bool isL1 = bid >= 384;
    if (isL1 ? (s < 1) : (s >= TT)) return;
    const int rem   = isL1 ? bid - 384 : bid;
    const int khalf = rem / 192;
    const int tile  = rem % 192;

    const int IN = isL1 ? 512 : 128;
    const int W  = IN + 512;
    const int KC = W >> 1;
    const int kbeg = khalf * KC;

    const float* fz  = ws + (isL1 ? OFF_FZ1 : OFF_FZ0);
    const float* fs  = ws + (isL1 ? OFF_FS1 : OFF_FS0);
    const float* fb  = ws + (isL1 ? OFF_FB1 : OFF_FB0);
    const float* swT = ws + (isL1 ? OFF_SWT1 : OFF_SWT0);
    const float* wih = isL1 ? w_ih1 : w_ih0;
    const float* whh = isL1 ? w_hh1 : w_hh0;
    const float* kb  = isL1 ? kb1 : kb0;
    float* p = ws + (isL1 ? OFF_P1 : OFF_P0) + (size_t)khalf * PSLICE;

    const int wv = threadIdx.x >> 6, lane = threadIdx.x & 63;

    // decode row group: 0..47 gates | 48..63 base | 64..191 spline planes
    int gtype, rowk, prow0, fmul, foff, rr = 0;
    if (tile < 48)      { gtype = 0; rowk = tile * 32 + wv * 8;        prow0 = rowk;            fmul = 1; foff = 0; }
    else if (tile < 64) { gtype = 1; rowk = (tile - 48) * 32 + wv * 8; prow0 = 1536 + rowk;     fmul = 1; foff = 0; }
    else { gtype = 2; rr = (tile - 64) >> 4; rowk = ((tile - 64) & 15) * 32 + wv * 8;
           prow0 = 2048 + rr * 512 + rowk; fmul = 8; foff = rr; }
    const float* fstream = (gtype == 0) ? fz : (gtype == 1 ? fs : fb);

    float acc[8];
#pragma unroll
    for (int j = 0; j < 8; ++j) acc[j] = 0.0f;

    for (int kc = kbeg; kc < kbeg + KC; kc += 64) {
        // ---- stage 64 k x 64 b feature chunk ----
#pragma unroll
        for (int q = 0; q < 4; ++q) {
            const int idx = threadIdx.x + q * 256;           // 0..1023
            const int kk = idx >> 4, b4 = (idx & 15) * 4;
            const float4 v = *(const float4*)(fstream +
                ((size_t)(kc + kk) * fmul + foff) * 64 + b4);
            *(float4*)&sf[kk * 64 + b4] = v;
        }
        __syncthreads();

        // ---- weight base for this chunk (never crosses IN mid-chunk) ----
        const float* wb; int wst;
        if (gtype == 0) {
            if (kc < IN) { wb = wih + (size_t)rowk * IN + kc;          wst = IN;  }
            else         { wb = whh + (size_t)rowk * 512 + (kc - IN);  wst = 512; }
        } else if (gtype == 1) {
            wb = kb + (size_t)rowk * W + kc;  wst = W;
        } else {
            wb = swT + ((size_t)rr * 512 + rowk) * W + kc;  wst = W;
        }

        // ---- 8 rows x 64 k: 1 ds_read feeds 8 FMAs ----
#pragma unroll 4
        for (int kk = 0; kk < 64; kk += 4) {
            const float f0 = sf[(kk + 0) * 64 + lane];
            const float f1 = sf[(kk + 1) * 64 + lane];
            const float f2 = sf[(kk + 2) * 64 + lane];
            const float f3 = sf[(kk + 3) * 64 + lane];
#pragma unroll
            for (int j = 0; j < 8; ++j) {
                const float4 w4 = *(const float4*)(wb + (size_t)j * wst + kk);
                acc[j] = fmaf(f0, w4.x, acc[j]);
                acc[j] = fmaf(f1, w4.y, acc[j]);
                acc[j] = fmaf(f2, w4.z, acc[j]);
                acc[j] = fmaf(f3, w4.w, acc[j]);
            }
        }
        __syncthreads();
    }

#pragma unroll
    for (int j = 0; j < 8; ++j)
        p[(size_t)(prow0 + j) * 64 + lane] = acc[j];
}

// phase B: cell updates (sum both K-halves) + feature generation.
__global__ __launch_bounds__(256) void phaseB_kernel(
    float* __restrict__ ws,
    const float* __restrict__ b_ih0, const float* __restrict__ b_hh0,
    const float* __restrict__ b_ih1, const float* __restrict__ b_hh1,
    const float* __restrict__ x, int s)
{
    float* h0 = ws + OFF_STATE;
    float* c0 = h0 + 32768;
    float* h1 = c0 + 32768;
    float* c1 = h1 + 32768;
    float* fz0 = ws + OFF_FZ0; float* fs0 = ws + OFF_FS0; float* fb0 = ws + OFF_FB0;
    float* fz1 = ws + OFF_FZ1; float* fs1 = ws + OFF_FS1; float* fb1 = ws + OFF_FB1;
    const float* p0 = ws + OFF_P0;
    const float* p1 = ws + OFF_P1;

    const int u = blockIdx.x * 256 + threadIdx.x;   // 288*256 = 73728
    if (u < 32768) {
        if (s >= TT) return;
        const int o = u >> 6, b = u & 63;
        auto P = [&](int r) { return p0[(size_t)r * 64 + b] + p0[PSLICE + (size_t)r * 64 + b]; };
        float si = P(o)        + b_ih0[o]      + b_hh0[o];
        float sf = P(512 + o)  + b_ih0[512+o]  + b_hh0[512+o];
        float sO = P(1024 + o) + b_ih0[1024+o] + b_hh0[1024+o];
        float sk = P(1536 + o);
#pragma unroll
        for (int rr = 0; rr < 8; ++rr) sk += P(2048 + rr * 512 + o);
        float ig = sigmoidf_(si), fg = sigmoidf_(sf), og = sigmoidf_(sO);
        float c = fg * c0[(size_t)o*64+b] + ig * sk;
        c0[(size_t)o*64+b] = c;
        float z = og * tanhf(c);
        h0[(size_t)o*64+b] = z;
        write_feats(z, o, b, fz1, fs1, fb1);        // L1 input features, t=s
        write_feats(z, 128 + o, b, fz0, fs0, fb0);  // L0 hidden features, t=s+1
    } else if (u < 65536) {
        if (s < 1) return;
        const int v = u - 32768, o = v >> 6, b = v & 63;
        auto P = [&](int r) { return p1[(size_t)r * 64 + b] + p1[PSLICE + (size_t)r * 64 + b]; };
        float si = P(o)        + b_ih1[o]      + b_hh1[o];
        float sf = P(512 + o)  + b_ih1[512+o]  + b_hh1[512+o];
        float sO = P(1024 + o) + b_ih1[1024+o] + b_hh1[1024+o];
        float sk = P(1536 + o);
#pragma unroll
        for (int rr = 0; rr < 8; ++rr) sk += P(2048 + rr * 512 + o);
        float ig = sigmoidf_(si), fg = sigmoidf_(sf), og = sigmoidf_(sO);
        float c = fg * c1[(size_t)o*64+b] + ig * sk;
        c1[(size_t)o*64+b] = c;
        float z = og * tanhf(c);
        h1[(size_t)o*64+b] = z;
        write_feats(z, 512 + o, b, fz1, fs1, fb1);  // L1 hidden features, t=s
    } else {
        if (s + 1 >= TT) return;
        const int v = u - 65536, k = v >> 6, b = v & 63;
        float z = x[((size_t)b * TT + (s + 1)) * 128 + k];
        write_feats(z, k, b, fz0, fs0, fb0);        // L0 x features, t=s+1
    }
}

// out[b][jo] = sum_o h1[o][b] * fc_w[jo][o] + fc_b[jo]  (fp32 out)
__global__ __launch_bounds__(256) void final_fc(
    const float* __restrict__ hT1, const float* __restrict__ fc_w,
    const float* __restrict__ fc_b, float* __restrict__ out)
{
    const int gid = blockIdx.x * 256 + threadIdx.x;   // 8192
    const int b = gid & 63, jo = gid >> 6;
    float a = fc_b[jo];
    for (int o = 0; o < 512; ++o)
        a = fmaf(hT1[(size_t)o * 64 + b], fc_w[(size_t)jo * 512 + o], a);
    out[(size_t)b * 128 + jo] = a;
}

} // namespace

extern "C" void kernel_launch(void* const* d_in, const int* in_sizes, int n_in,
                              void* d_out, int out_size, void* d_ws, size_t ws_size,
                              hipStream_t stream) {
    (void)out_size;
    float* out = (float*)d_out;

    static const int EXP_SIZES[15] = {
        64 * 256 * 128, 1536 * 128, 1536 * 512, 1536, 1536,
        512 * 640, 512 * 640 * 8,
        1536 * 512, 1536 * 512, 1536, 1536,
        512 * 1024, 512 * 1024 * 8,
        128 * 512, 128
    };
    if (n_in != 15) { sentinel_kernel<<<32, 256, 0, stream>>>(out, 111.0f); return; }
    for (int i = 0; i < 15; ++i)
        if (in_sizes[i] != EXP_SIZES[i]) {
            sentinel_kernel<<<32, 256, 0, stream>>>(out, 200.0f * (i + 1)); return;
        }
    if (ws_size < WS_NEED) { sentinel_kernel<<<32, 256, 0, stream>>>(out, 7777.0f); return; }

    const float* x     = (const float*)d_in[0];
    const float* w_ih0 = (const float*)d_in[1];
    const float* w_hh0 = (const float*)d_in[2];
    const float* b_ih0 = (const float*)d_in[3];
    const float* b_hh0 = (const float*)d_in[4];
    const float* kb0   = (const float*)d_in[5];
    const float* ksp0  = (const float*)d_in[6];
    const float* w_ih1 = (const float*)d_in[7];
    const float* w_hh1 = (const float*)d_in[8];
    const float* b_ih1 = (const float*)d_in[9];
    const float* b_hh1 = (const float*)d_in[10];
    const float* kb1   = (const float*)d_in[11];
    const float* ksp1  = (const float*)d_in[12];
    const float* fc_w  = (const float*)d_in[13];
    const float* fc_b  = (const float*)d_in[14];

    float* ws = (float*)d_ws;

    prologue_kernel<<<800, 256, 0, stream>>>(x, ws);
    transpose_sw<640><<<1280, 256, 0, stream>>>(ksp0, ws + OFF_SWT0);
    transpose_sw<1024><<<2048, 256, 0, stream>>>(ksp1, ws + OFF_SWT1);

    for (int s = 0; s <= TT; ++s) {
        phaseA_kernel<<<768, 256, 0, stream>>>(
            ws, w_ih0, w_hh0, kb0, w_ih1, w_hh1, kb1, s);
        phaseB_kernel<<<288, 256, 0, stream>>>(
            ws, b_ih0, b_hh0, b_ih1, b_hh1, x, s);
    }

    final_fc<<<32, 256, 0, stream>>>(ws + OFF_STATE + 2 * 32768, fc_w, fc_b, out);
}

// Round 12
// 8326.710 us; speedup vs baseline: 14.6215x; 2.8183x over previous
//
#include <hip/hip_runtime.h>
#include <math.h>
#include <stdint.h>

namespace {

typedef __attribute__((ext_vector_type(8))) short short8v;   // 8 bf16 = 4 VGPR
typedef __attribute__((ext_vector_type(4))) float f32x4;

constexpr int TT = 256;

// ---- ws float offsets (total 9,551,872 floats = 38.2 MB <= proven 38.8) ----
constexpr size_t OFF_ST   = 0;         // c0T,h1T,c1T  [3][64][512]
constexpr size_t OFF_P0   = 98304;     // [2][64][6144]
constexpr size_t OFF_P1   = 884736;    // [2][64][6144]
constexpr size_t OFF_SWT0 = 1671168;   // [8][512][640]  fp32
constexpr size_t OFF_SWT1 = 4292608;   // [8][512][1024] fp32
constexpr size_t OFF_FEAT = 8486912;   // ushort area (1,064,960 floats)
constexpr size_t WS_NEED  = 9551872ull * 4;

// ---- ushort offsets within FEAT ----
constexpr size_t FZ0H = 0,       FZ0L = 40960,  FS0H = 81920,  FS0L = 122880;
constexpr size_t FB0H = 163840,  FB0L = 491520;                 // planes 64*640
constexpr size_t L1F  = 819200;
constexpr size_t FZ1H = L1F,          FZ1L = L1F + 65536;
constexpr size_t FS1H = L1F + 131072, FS1L = L1F + 196608;
constexpr size_t FB1H = L1F + 262144, FB1L = L1F + 786432;      // planes 64*1024

__device__ __forceinline__ float sigmoidf_(float v) { return 1.0f / (1.0f + expf(-v)); }

__device__ __forceinline__ ushort bf16h(float v) {          // RNE f32 -> bf16 bits
    uint32_t u = __float_as_uint(v);
    return (ushort)((u + 0x7fffu + ((u >> 16) & 1u)) >> 16);
}
__device__ __forceinline__ float bf16f(ushort h) { return __uint_as_float(((uint32_t)h) << 16); }
__device__ __forceinline__ void put2(ushort* hi, ushort* lo, size_t idx, float v) {
    ushort h = bf16h(v); hi[idx] = h; lo[idx] = bf16h(v - bf16f(h));
}

// Cox-de Boor, GRID_SIZE=5, ORDER=3 (verified across rounds 7-11)
__device__ __forceinline__ void bspline8(float x, float* out) {
    const float KG[12] = {-2.2f,-1.8f,-1.4f,-1.0f,-0.6f,-0.2f,
                           0.2f, 0.6f, 1.0f, 1.4f, 1.8f, 2.2f};
    float b[11];
#pragma unroll
    for (int i = 0; i < 11; ++i)
        b[i] = (x >= KG[i] && x < KG[i + 1]) ? 1.0f : 0.0f;
#pragma unroll
    for (int p = 1; p <= 3; ++p) {
#pragma unroll
        for (int i = 0; i + p < 11; ++i) {
            float l = (x - KG[i])         * (1.0f / (KG[i + p] - KG[i]));
            float r = (KG[i + p + 1] - x) * (1.0f / (KG[i + p + 1] - KG[i + 1]));
            b[i] = l * b[i] + r * b[i + 1];
        }
    }
#pragma unroll
    for (int i = 0; i < 8; ++i) out[i] = b[i];
}

// z, silu(z), 8 bases -> hi/lo bf16, transposed [b][k] layout
__device__ __forceinline__ void write_featsT(float z, ushort* fe,
        size_t zh, size_t zl, size_t sh, size_t sl, size_t bh, size_t bl,
        size_t pstride, size_t idx)
{
    put2(fe + zh, fe + zl, idx, z);
    put2(fe + sh, fe + sl, idx, z / (1.0f + expf(-z)));
    float bs[8];
    bspline8(z, bs);
#pragma unroll
    for (int r = 0; r < 8; ++r)
        put2(fe + bh + (size_t)r * pstride, fe + bl + (size_t)r * pstride, idx, bs[r]);
}

__global__ __launch_bounds__(256) void sentinel_kernel(float* out, float v) {
    int i = blockIdx.x * 256 + threadIdx.x;
    if (i < 8192) out[i] = v;
}

// states zero + t=0 x-features + zero-state hidden features for both layers
__global__ __launch_bounds__(256) void prologue_kernel(
    const float* __restrict__ x, float* __restrict__ ws)
{
    ushort* fe = (ushort*)(ws + OFF_FEAT);
    const int g = blockIdx.x * 256 + threadIdx.x;    // 672*256 = 172032
    if (g < 98304) {
        ws[OFF_ST + g] = 0.0f;                       // c0T,h1T,c1T
    } else if (g < 106496) {                         // t=0 x feats (k<128)
        const int i = g - 98304, k = i & 127, b = i >> 7;
        write_featsT(x[((size_t)b * TT) * 128 + k], fe,
                     FZ0H, FZ0L, FS0H, FS0L, FB0H, FB0L, 40960, (size_t)b * 640 + k);
    } else if (g < 139264) {                         // L0 hidden feats h0(-1)=0
        const int i = g - 106496, o = i & 511, b = i >> 9;
        write_featsT(0.0f, fe, FZ0H, FZ0L, FS0H, FS0L, FB0H, FB0L,
                     40960, (size_t)b * 640 + 128 + o);
    } else {                                         // L1 hidden feats h1(-1)=0
        const int i = g - 139264, o = i & 511, b = i >> 9;
        write_featsT(0.0f, fe, FZ1H, FZ1L, FS1H, FS1L, FB1H, FB1L,
                     65536, (size_t)b * 1024 + 512 + o);
    }
}

// sw [512][W][8] -> swT [8][512][W] fp32 (A-fragment wants k contiguous)
template <int W>
__global__ __launch_bounds__(256) void transpose_sw(const float* __restrict__ sw,
                                                    float* __restrict__ swT) {
    const int i = blockIdx.x * 256 + threadIdx.x;   // over 512*W
    float v[8];
#pragma unroll
    for (int r = 0; r < 8; ++r) v[r] = sw[(size_t)i * 8 + r];
#pragma unroll
    for (int r = 0; r < 8; ++r) swT[(size_t)r * 512 * W + i] = v[r];
}

// phase A: MFMA GEMM, fp32-equivalent via split-bf16 (3 products).
// 1536 wave-tasks = 2 layers x 384 row-tiles x 2 K-halves; 768 blocks x 128 thr.
// A: weight fp32 load -> hi/lo bf16 split in regs. B: feature bf16 hi/lo [b][k].
// Fragment maps (m89-verified C/D): A row=lane&15,k=(lane>>4)*8+j;
// B col=lane&15, same k; C col=lane&15, row=(lane>>4)*4+reg.
__global__ __launch_bounds__(128) void phaseA_kernel(
    float* __restrict__ ws,
    const float* __restrict__ w_ih0, const float* __restrict__ w_hh0,
    const float* __restrict__ kb0,
    const float* __restrict__ w_ih1, const float* __restrict__ w_hh1,
    const float* __restrict__ kb1, int s)
{
    const int lane = threadIdx.x & 63;
    const int wv   = __builtin_amdgcn_readfirstlane((int)(threadIdx.x >> 6));
    const int wid  = blockIdx.x * 2 + wv;            // 0..1535
    const bool isL1 = wid >= 768;
    if (isL1 ? (s < 1) : (s >= TT)) return;
    const int r    = isL1 ? wid - 768 : wid;
    const int tile = r >> 1, khalf = r & 1;
    const int IN = isL1 ? 512 : 128, W = IN + 512, KC = W >> 1, NSL = KC >> 5;

    const ushort* fe = (const ushort*)(ws + OFF_FEAT);
    float* p = ws + (isL1 ? OFF_P1 : OFF_P0) + (size_t)khalf * 393216;

    const int m = lane & 15, kg = lane >> 4;
    const int o0 = tile * 16;
    const float* wrow_a; const float* wrow_b = nullptr;
    const ushort *fhi, *flo;
    if (tile < 96) {                                  // gate rows (z features)
        wrow_a = (isL1 ? w_ih1 : w_ih0) + (size_t)(o0 + m) * IN;
        wrow_b = (isL1 ? w_hh1 : w_hh0) + (size_t)(o0 + m) * 512;
        fhi = fe + (isL1 ? FZ1H : FZ0H);  flo = fe + (isL1 ? FZ1L : FZ0L);
    } else if (tile < 128) {                          // base rows (silu features)
        wrow_a = (isL1 ? kb1 : kb0) + (size_t)((tile - 96) * 16 + m) * W;
        fhi = fe + (isL1 ? FS1H : FS0H);  flo = fe + (isL1 ? FS1L : FS0L);
    } else {                                          // spline rows (basis features)
        const int rr = (tile - 128) >> 5, op = ((tile - 128) & 31) * 16 + m;
        wrow_a = ws + (isL1 ? OFF_SWT1 : OFF_SWT0) + ((size_t)rr * 512 + op) * W;
        fhi = fe + (isL1 ? FB1H : FB0H) + (size_t)rr * 64 * W;
        flo = fe + (isL1 ? FB1L : FB0L) + (size_t)rr * 64 * W;
    }

    f32x4 acc[4] = {{0,0,0,0},{0,0,0,0},{0,0,0,0},{0,0,0,0}};
    const int kbase = khalf * KC;

    for (int sl = 0; sl < NSL; ++sl) {
        const int k0 = kbase + sl * 32;
        const int kk = k0 + kg * 8;
        const float* wp = (tile < 96 && k0 >= IN) ? (wrow_b + (kk - IN)) : (wrow_a + kk);
        float4 wa = *(const float4*)wp;
        float4 wb4 = *(const float4*)(wp + 4);
        const float wvv[8] = {wa.x, wa.y, wa.z, wa.w, wb4.x, wb4.y, wb4.z, wb4.w};
        short8v whi, wlo;
#pragma unroll
        for (int j = 0; j < 8; ++j) {
            ushort h = bf16h(wvv[j]);
            whi[j] = (short)h;
            wlo[j] = (short)bf16h(wvv[j] - bf16f(h));
        }
#pragma unroll
        for (int bt = 0; bt < 4; ++bt) {
            const size_t fidx = (size_t)(bt * 16 + m) * W + kk;
            short8v bh = *(const short8v*)(fhi + fidx);
            short8v bl = *(const short8v*)(flo + fidx);
            acc[bt] = __builtin_amdgcn_mfma_f32_16x16x32_bf16(whi, bh, acc[bt], 0, 0, 0);
            acc[bt] = __builtin_amdgcn_mfma_f32_16x16x32_bf16(whi, bl, acc[bt], 0, 0, 0);
            acc[bt] = __builtin_amdgcn_mfma_f32_16x16x32_bf16(wlo, bh, acc[bt], 0, 0, 0);
        }
    }

#pragma unroll
    for (int bt = 0; bt < 4; ++bt) {
        float* dst = p + (size_t)(bt * 16 + m) * 6144 + o0 + kg * 4;
        *(float4*)dst = (float4){acc[bt][0], acc[bt][1], acc[bt][2], acc[bt][3]};
    }
}

// phase B: cell updates (sum 2 K-halves) + feature generation; o-fast mapping.
__global__ __launch_bounds__(256) void phaseB_kernel(
    float* __restrict__ ws,
    const float* __restrict__ b_ih0, const float* __restrict__ b_hh0,
    const float* __restrict__ b_ih1, const float* __restrict__ b_hh1,
    const float* __restrict__ x, int s)
{
    ushort* fe = (ushort*)(ws + OFF_FEAT);
    float* c0T = ws + OFF_ST;
    float* h1T = c0T + 32768;
    float* c1T = h1T + 32768;
    const float* p0 = ws + OFF_P0;
    const float* p1 = ws + OFF_P1;

    const int u = blockIdx.x * 256 + threadIdx.x;    // 288*256 = 73728
    if (u < 32768) {
        if (s >= TT) return;
        const int o = u & 511, b = u >> 9;
        auto P = [&](int rw) {
            return p0[(size_t)b * 6144 + rw] + p0[393216 + (size_t)b * 6144 + rw];
        };
        float si = P(o)        + b_ih0[o]        + b_hh0[o];
        float sf = P(512 + o)  + b_ih0[512 + o]  + b_hh0[512 + o];
        float sO = P(1024 + o) + b_ih0[1024 + o] + b_hh0[1024 + o];
        float sk = P(1536 + o);
#pragma unroll
        for (int rr = 0; rr < 8; ++rr) sk += P(2048 + rr * 512 + o);
        float ig = sigmoidf_(si), fg = sigmoidf_(sf), og = sigmoidf_(sO);
        float c = fg * c0T[(size_t)b * 512 + o] + ig * sk;
        c0T[(size_t)b * 512 + o] = c;
        float z = og * tanhf(c);
        write_featsT(z, fe, FZ1H, FZ1L, FS1H, FS1L, FB1H, FB1L,
                     65536, (size_t)b * 1024 + o);            // L1 input, t=s
        write_featsT(z, fe, FZ0H, FZ0L, FS0H, FS0L, FB0H, FB0L,
                     40960, (size_t)b * 640 + 128 + o);       // L0 hidden, t=s+1
    } else if (u < 65536) {
        if (s < 1) return;
        const int v = u - 32768, o = v & 511, b = v >> 9;
        auto P = [&](int rw) {
            return p1[(size_t)b * 6144 + rw] + p1[393216 + (size_t)b * 6144 + rw];
        };
        float si = P(o)        + b_ih1[o]        + b_hh1[o];
        float sf = P(512 + o)  + b_ih1[512 + o]  + b_hh1[512 + o];
        float sO = P(1024 + o) + b_ih1[1024 + o] + b_hh1[1024 + o];
        float sk = P(1536 + o);
#pragma unroll
        for (int rr = 0; rr < 8; ++rr) sk += P(2048 + rr * 512 + o);
        float ig = sigmoidf_(si), fg = sigmoidf_(sf), og = sigmoidf_(sO);
        float c = fg * c1T[(size_t)b * 512 + o] + ig * sk;
        c1T[(size_t)b * 512 + o] = c;
        float z = og * tanhf(c);
        h1T[(size_t)b * 512 + o] = z;
        write_featsT(z, fe, FZ1H, FZ1L, FS1H, FS1L, FB1H, FB1L,
                     65536, (size_t)b * 1024 + 512 + o);      // L1 hidden, t=s
    } else {
        if (s + 1 >= TT) return;
        const int v = u - 65536, k = v & 127, b = v >> 7;
        float z = x[((size_t)b * TT + (s + 1)) * 128 + k];
        write_featsT(z, fe, FZ0H, FZ0L, FS0H, FS0L, FB0H, FB0L,
                     40960, (size_t)b * 640 + k);             // L0 x, t=s+1
    }
}

// out[b][jo] = h1T[b] . fc_w[jo] + fc_b[jo]  (fp32 out)
__global__ __launch_bounds__(256) void final_fc(
    const float* __restrict__ h1T, const float* __restrict__ fc_w,
    const float* __restrict__ fc_b, float* __restrict__ out)
{
    const int gid = blockIdx.x * 256 + threadIdx.x;   // 8192
    const int b = gid & 63, jo = gid >> 6;
    float a = fc_b[jo];
    const float* hr = h1T + (size_t)b * 512;
    const float* wr = fc_w + (size_t)jo * 512;
    for (int o = 0; o < 512; o += 4) {
        float4 h4 = *(const float4*)(hr + o);
        float4 w4 = *(const float4*)(wr + o);
        a = fmaf(h4.x, w4.x, a); a = fmaf(h4.y, w4.y, a);
        a = fmaf(h4.z, w4.z, a); a = fmaf(h4.w, w4.w, a);
    }
    out[(size_t)b * 128 + jo] = a;
}

} // namespace

extern "C" void kernel_launch(void* const* d_in, const int* in_sizes, int n_in,
                              void* d_out, int out_size, void* d_ws, size_t ws_size,
                              hipStream_t stream) {
    (void)out_size;
    float* out = (float*)d_out;

    static const int EXP_SIZES[15] = {
        64 * 256 * 128, 1536 * 128, 1536 * 512, 1536, 1536,
        512 * 640, 512 * 640 * 8,
        1536 * 512, 1536 * 512, 1536, 1536,
        512 * 1024, 512 * 1024 * 8,
        128 * 512, 128
    };
    if (n_in != 15) { sentinel_kernel<<<32, 256, 0, stream>>>(out, 111.0f); return; }
    for (int i = 0; i < 15; ++i)
        if (in_sizes[i] != EXP_SIZES[i]) {
            sentinel_kernel<<<32, 256, 0, stream>>>(out, 200.0f * (i + 1)); return;
        }
    if (ws_size < WS_NEED) { sentinel_kernel<<<32, 256, 0, stream>>>(out, 7777.0f); return; }

    const float* x     = (const float*)d_in[0];
    const float* w_ih0 = (const float*)d_in[1];
    const float* w_hh0 = (const float*)d_in[2];
    const float* b_ih0 = (const float*)d_in[3];
    const float* b_hh0 = (const float*)d_in[4];
    const float* kb0   = (const float*)d_in[5];
    const float* ksp0  = (const float*)d_in[6];
    const float* w_ih1 = (const float*)d_in[7];
    const float* w_hh1 = (const float*)d_in[8];
    const float* b_ih1 = (const float*)d_in[9];
    const float* b_hh1 = (const float*)d_in[10];
    const float* kb1   = (const float*)d_in[11];
    const float* ksp1  = (const float*)d_in[12];
    const float* fc_w  = (const float*)d_in[13];
    const float* fc_b  = (const float*)d_in[14];

    float* ws = (float*)d_ws;

    prologue_kernel<<<672, 256, 0, stream>>>(x, ws);
    transpose_sw<640><<<1280, 256, 0, stream>>>(ksp0, ws + OFF_SWT0);
    transpose_sw<1024><<<2048, 256, 0, stream>>>(ksp1, ws + OFF_SWT1);

    for (int s = 0; s <= TT; ++s) {
        phaseA_kernel<<<768, 128, 0, stream>>>(
            ws, w_ih0, w_hh0, kb0, w_ih1, w_hh1, kb1, s);
        phaseB_kernel<<<288, 256, 0, stream>>>(
            ws, b_ih0, b_hh0, b_ih1, b_hh1, x, s);
    }

    final_fc<<<32, 256, 0, stream>>>(ws + OFF_ST + 32768, fc_w, fc_b, out);
}